// Round 8
// baseline (40.676 us; speedup 1.0000x reference)
//
#include <hip/hip_runtime.h>
#include <cstdint>

#define B_    2048
#define T_    2048
#define TD    7
#define NCHK  128        // chunks per row (= threads per block)
#define IDENT 0x4688u    // identity map: 0|1<<3|2<<6|3<<9|4<<12

// compose packed 5-slot maps: r[j] = f[g[j]]
__device__ __forceinline__ uint32_t mcompose(uint32_t f, uint32_t g) {
    uint32_t r = 0;
#pragma unroll
    for (int j = 0; j < 5; ++j) {
        uint32_t gj = (g >> (3 * j)) & 7u;
        r |= ((f >> (3 * gj)) & 7u) << (3 * j);
    }
    return r;
}

// pack two f32 -> bf16 pair (RNE), low half = first arg
__device__ __forceinline__ uint32_t cvtpk(float lo, float hi) {
    uint32_t r;
    asm("v_cvt_pk_bf16_f32 %0, %1, %2" : "=v"(r) : "v"(lo), "v"(hi));
    return r;
}

__device__ __forceinline__ float bfld(const uint16_t* __restrict__ xs, int h) {
    return __uint_as_float(((uint32_t)xs[h]) << 16);
}

// halo step: dp update only. P=true -> predicated by pred.
template<bool P>
__device__ __forceinline__ void hstep(const uint16_t* __restrict__ xs, int h, bool pred,
                                      float (&dp)[5], const float (&tr)[5][5]) {
    float nd[5];
#pragma unroll
    for (int j = 0; j < 5; ++j) {
        float v = fmaxf(fmaxf(fmaxf(fmaxf(dp[0] + tr[0][j], dp[1] + tr[1][j]),
                                    dp[2] + tr[2][j]), dp[3] + tr[3][j]),
                        dp[4] + tr[4][j]);
        nd[j] = v + bfld(xs, h + j);
    }
#pragma unroll
    for (int j = 0; j < 5; ++j) dp[j] = (P && !pred) ? dp[j] : nd[j];
}

// live step: mantissa-embedded argmax. SEL=true -> mask/identity select needed.
template<bool SEL>
__device__ __forceinline__ uint32_t lstep(const uint16_t* __restrict__ xs, int h, bool mm,
                                          float (&dp)[5], const float (&tr)[5][5],
                                          uint32_t& rho) {
    float nd[5]; int aa[5]; uint32_t pk = 0;
#pragma unroll
    for (int j = 0; j < 5; ++j) {
        float s[5];
#pragma unroll
        for (int i = 0; i < 5; ++i) {
            float f = dp[i] + tr[i][j];
            uint32_t u = (__float_as_uint(f) & ~7u) | (uint32_t)(7 - i);  // v_and_or_b32
            s[i] = __uint_as_float(u);
        }
        float m = fmaxf(fmaxf(fmaxf(fmaxf(s[0], s[1]), s[2]), s[3]), s[4]); // 2x v_max3
        int a = 7 - (int)(__float_as_uint(m) & 7u);
        float v = m + bfld(xs, h + j);
        if (SEL) { a = mm ? a : j; nd[j] = mm ? v : dp[j]; }
        else     { nd[j] = v; }
        aa[j] = a;
        pk |= ((uint32_t)a) << (3 * j);
    }
    uint32_t nr = 0;
#pragma unroll
    for (int j = 0; j < 5; ++j) nr |= ((rho >> (3 * aa[j])) & 7u) << (3 * j);
    rho = nr;
#pragma unroll
    for (int j = 0; j < 5; ++j) dp[j] = nd[j];
    return pk;
}

// halo warm-up (16-step anchor) + exact live forward (16 steps), bp in registers
template<bool AM>
__device__ __forceinline__ void fwd(const uint16_t* __restrict__ xs,
                                    const uint16_t* __restrict__ msk, int cc,
                                    const float (&tr)[5][5], const float (&ts)[5],
                                    float (&dp)[5], float (&dpE)[5],
                                    uint32_t (&acc)[8], uint32_t& rho) {
    const int hbase = (cc > 0) ? 82 * (cc - 1) : 0;   // halo chunk = cc-1
#pragma unroll
    for (int j = 0; j < 5; ++j) dp[j] = bfld(xs, hbase + j);
    if (cc <= 1) {                                    // s0==0: exact start
#pragma unroll
        for (int j = 0; j < 5; ++j) dp[j] += ts[j];
    }
    const uint32_t mh = AM ? 0xFFFFu : ((cc > 0) ? (uint32_t)msk[cc - 1] : 0u);
#pragma unroll
    for (int h = 1; h <= 15; ++h) {
        if (AM) hstep<false>(xs, hbase + 5 * h, true, dp, tr);
        else    hstep<true >(xs, hbase + 5 * h, ((mh >> h) & 1u) != 0, dp, tr);
    }
    if (AM && cc == 0) {       // AM halo ran unconditionally; restore exact t=0 init
#pragma unroll
        for (int j = 0; j < 5; ++j) dp[j] = bfld(xs, j) + ts[j];
    }
#pragma unroll
    for (int j = 0; j < 5; ++j) dpE[j] = (cc == 0) ? 0.0f : dp[j];

    rho = IDENT;
    const int lb = 82 * cc;
    const uint32_t ml = AM ? 0xFFFFu : (uint32_t)msk[cc];
    acc[0] = lstep<true>(xs, lb, (cc != 0) && ((ml & 1u) != 0), dp, tr, rho);
#pragma unroll
    for (int l = 1; l < 16; ++l) {
        uint32_t pk;
        if (AM) pk = lstep<false>(xs, lb + 5 * l, true, dp, tr, rho);
        else    pk = lstep<true >(xs, lb + 5 * l, ((ml >> l) & 1u) != 0, dp, tr, rho);
        if (l & 1) acc[l >> 1] |= pk << 16;
        else       acc[l >> 1]  = pk;
    }
}

__global__ __launch_bounds__(128) void k_all(
    const float* __restrict__ x, const int* __restrict__ mask,
    const float* __restrict__ tf, float* __restrict__ out)
{
    __shared__ uint16_t xs[10496];   // 128 chunks * 82 halfwords (bf16, skewed)
    __shared__ uint16_t msk[NCHK];   // 16 mask bits per chunk
    __shared__ uint32_t tot[2];
    __shared__ float    part[2];
    __shared__ int      lastS;

    const int b = blockIdx.x, c = threadIdx.x;
    const int lane = c & 63, w = c >> 6;

    // ---- stage x: coalesced float4 loads -> bf16 pairs -> skewed LDS ----
    const float4* gx = (const float4*)(x + (size_t)b * (T_ * 5));
#pragma unroll
    for (int q = 0; q < 20; ++q) {
        int fi = c + 128 * q;
        float4 v = gx[fi];
        int e0 = 4 * fi;
        int k  = (e0 * 52429) >> 22;          // e0/80 (exact for e0 < 26000)
        int h0 = e0 + 2 * k;                  // +2 halfword pad per 16-step chunk
        *(uint32_t*)(xs + h0)     = cvtpk(v.x, v.y);
        *(uint32_t*)(xs + h0 + 2) = cvtpk(v.z, v.w);
    }
    // ---- stage mask bits: thread c owns chunk c's 16 steps ----
    uint32_t mb = 0;
    {
        const int4* gm = (const int4*)(mask + (size_t)b * T_);
#pragma unroll
        for (int q = 0; q < 4; ++q) {
            int4 a = gm[4 * c + q];
            mb |= (a.x ? 1u : 0u) << (4 * q);
            mb |= (a.y ? 1u : 0u) << (4 * q + 1);
            mb |= (a.z ? 1u : 0u) << (4 * q + 2);
            mb |= (a.w ? 1u : 0u) << (4 * q + 3);
        }
        msk[c] = (uint16_t)mb;
    }

    float tr[5][5], ts[5], te[5];
#pragma unroll
    for (int i = 0; i < 5; ++i)
#pragma unroll
        for (int j = 0; j < 5; ++j) tr[i][j] = tf[i * TD + j];
#pragma unroll
    for (int j = 0; j < 5; ++j) ts[j] = tf[5 * TD + j];
#pragma unroll
    for (int j = 0; j < 5; ++j) te[j] = tf[j * TD + 6];

    const int allones = __syncthreads_and(mb == 0xFFFFu);

    float dp[5], dpE[5]; uint32_t acc[8], rho;
    if (allones) fwd<true >(xs, msk, c, tr, ts, dp, dpE, acc, rho);
    else         fwd<false>(xs, msk, c, tr, ts, dp, dpE, acc, rho);

    // exact per-chunk segment score of the decoded tree (within-lane telescoping)
    float svec[5];
#pragma unroll
    for (int j = 0; j < 5; ++j) {
        int r = (rho >> (3 * j)) & 7;
        float e = dpE[0];
        e = (r == 1) ? dpE[1] : e;
        e = (r == 2) ? dpE[2] : e;
        e = (r == 3) ? dpE[3] : e;
        e = (r == 4) ? dpE[4] : e;
        svec[j] = dp[j] - e;
    }

    // ---- intra-wave suffix composition (shfl, no barriers) ----
    uint32_t I = rho;
#pragma unroll
    for (int d = 1; d < 64; d <<= 1) {
        uint32_t oth = __shfl_down(I, d);
        uint32_t cm  = mcompose(I, oth);
        I = (lane + d < 64) ? cm : I;
    }
    if (lane == 0) tot[w] = I;
    if (c == NCHK - 1) {
        float best = dp[0] + te[0]; int last = 0;
#pragma unroll
        for (int j = 1; j < 5; ++j) {
            float s = dp[j] + te[j];
            if (s > best) { best = s; last = j; }
        }
        lastS = last;
    }
    __syncthreads();

    uint32_t Tw = (w == 0) ? tot[1] : IDENT;
    uint32_t Ex = __shfl_down(I, 1);
    uint32_t M  = (lane < 63) ? mcompose(Ex, Tw) : Tw;
    const int last = lastS;
    const int ec = (M >> (3 * last)) & 7;      // class at end of chunk c

    // ---- exact telescoped score: wave reduce + 2 partials ----
    {
        float v = svec[0];
        v = (ec == 1) ? svec[1] : v;
        v = (ec == 2) ? svec[2] : v;
        v = (ec == 3) ? svec[3] : v;
        v = (ec == 4) ? svec[4] : v;
        if (c == NCHK - 1) v += te[last];
#pragma unroll
        for (int off = 1; off < 64; off <<= 1) v += __shfl_xor(v, off);
        if (lane == 0) part[w] = v;
    }
    __syncthreads();
    if (c == 0) out[b] = part[0] + part[1];

    // ---- path decode from register bp ----
    float pv[16];
    int e = ec;
#pragma unroll
    for (int l = 15; l >= 0; --l) {
        pv[l] = (float)e;
        uint32_t p = (acc[l >> 1] >> (16 * (l & 1))) & 0xFFFFu;
        e = (p >> (3 * e)) & 7;
    }
    float* path = out + B_ + (size_t)b * T_ + c * 16;
#pragma unroll
    for (int q = 0; q < 4; ++q) {
        float4 v; v.x = pv[4*q]; v.y = pv[4*q+1]; v.z = pv[4*q+2]; v.w = pv[4*q+3];
        ((float4*)path)[q] = v;
    }
}

extern "C" void kernel_launch(void* const* d_in, const int* in_sizes, int n_in,
                              void* d_out, int out_size, void* d_ws, size_t ws_size,
                              hipStream_t stream) {
    const float* x         = (const float*)d_in[0];
    const int*   mask      = (const int*)d_in[1];
    const float* transform = (const float*)d_in[2];
    float*       out       = (float*)d_out;

    hipLaunchKernelGGL(k_all, dim3(B_), dim3(128), 0, stream,
                       x, mask, transform, out);
}

// Round 9
// 38.708 us; speedup vs baseline: 1.0509x; 1.0509x over previous
//
#include <hip/hip_runtime.h>
#include <cstdint>

#define B_    2048
#define T_    2048
#define TD    7
#define NCHK  128        // chunks per row (= threads per block)
#define IDENT 0x4688u    // identity map: 0|1<<3|2<<6|3<<9|4<<12

// compose packed 5-slot maps: r[j] = f[g[j]]
__device__ __forceinline__ uint32_t mcompose(uint32_t f, uint32_t g) {
    uint32_t r = 0;
#pragma unroll
    for (int j = 0; j < 5; ++j) {
        uint32_t gj = (g >> (3 * j)) & 7u;
        r |= ((f >> (3 * gj)) & 7u) << (3 * j);
    }
    return r;
}

// pack two f32 -> bf16 pair (RNE), low half = first arg
__device__ __forceinline__ uint32_t cvtpk(float lo, float hi) {
    uint32_t r;
    asm("v_cvt_pk_bf16_f32 %0, %1, %2" : "=v"(r) : "v"(lo), "v"(hi));
    return r;
}

__device__ __forceinline__ float bfld(const uint16_t* __restrict__ xs, int h) {
    return __uint_as_float(((uint32_t)xs[h]) << 16);
}

// halo step: dp update only. P=true -> predicated by pred.
template<bool P>
__device__ __forceinline__ void hstep(const uint16_t* __restrict__ xs, int h, bool pred,
                                      float (&dp)[5], const float (&tr)[5][5]) {
    float nd[5];
#pragma unroll
    for (int j = 0; j < 5; ++j) {
        float v = fmaxf(fmaxf(fmaxf(fmaxf(dp[0] + tr[0][j], dp[1] + tr[1][j]),
                                    dp[2] + tr[2][j]), dp[3] + tr[3][j]),
                        dp[4] + tr[4][j]);
        nd[j] = v + bfld(xs, h + j);
    }
#pragma unroll
    for (int j = 0; j < 5; ++j) dp[j] = (P && !pred) ? dp[j] : nd[j];
}

// live step: mantissa-embedded argmax. SEL=true -> mask/identity select needed.
template<bool SEL>
__device__ __forceinline__ uint32_t lstep(const uint16_t* __restrict__ xs, int h, bool mm,
                                          float (&dp)[5], const float (&tr)[5][5],
                                          uint32_t& rho) {
    float nd[5]; int aa[5]; uint32_t pk = 0;
#pragma unroll
    for (int j = 0; j < 5; ++j) {
        float s[5];
#pragma unroll
        for (int i = 0; i < 5; ++i) {
            float f = dp[i] + tr[i][j];
            uint32_t u = (__float_as_uint(f) & ~7u) | (uint32_t)(7 - i);  // v_and_or_b32
            s[i] = __uint_as_float(u);
        }
        float m = fmaxf(fmaxf(fmaxf(fmaxf(s[0], s[1]), s[2]), s[3]), s[4]); // 2x v_max3
        int a = 7 - (int)(__float_as_uint(m) & 7u);
        float v = m + bfld(xs, h + j);
        if (SEL) { a = mm ? a : j; nd[j] = mm ? v : dp[j]; }
        else     { nd[j] = v; }
        aa[j] = a;
        pk |= ((uint32_t)a) << (3 * j);
    }
    uint32_t nr = 0;
#pragma unroll
    for (int j = 0; j < 5; ++j) nr |= ((rho >> (3 * aa[j])) & 7u) << (3 * j);
    rho = nr;
#pragma unroll
    for (int j = 0; j < 5; ++j) dp[j] = nd[j];
    return pk;
}

// halo warm-up (16-step anchor) + exact live forward (16 steps), bp in registers
template<bool AM>
__device__ __forceinline__ void fwd(const uint16_t* __restrict__ xs,
                                    const uint16_t* __restrict__ msk, int cc,
                                    const float (&tr)[5][5], const float (&ts)[5],
                                    float (&dp)[5], float (&dpE)[5],
                                    uint32_t (&acc)[8], uint32_t& rho) {
    const int hbase = (cc > 0) ? 82 * (cc - 1) : 0;   // halo chunk = cc-1
#pragma unroll
    for (int j = 0; j < 5; ++j) dp[j] = bfld(xs, hbase + j);
    if (cc <= 1) {                                    // s0==0: exact start
#pragma unroll
        for (int j = 0; j < 5; ++j) dp[j] += ts[j];
    }
    const uint32_t mh = AM ? 0xFFFFu : ((cc > 0) ? (uint32_t)msk[cc - 1] : 0u);
#pragma unroll
    for (int h = 1; h <= 15; ++h) {
        if (AM) hstep<false>(xs, hbase + 5 * h, true, dp, tr);
        else    hstep<true >(xs, hbase + 5 * h, ((mh >> h) & 1u) != 0, dp, tr);
    }
    if (AM && cc == 0) {       // AM halo ran unconditionally; restore exact t=0 init
#pragma unroll
        for (int j = 0; j < 5; ++j) dp[j] = bfld(xs, j) + ts[j];
    }
#pragma unroll
    for (int j = 0; j < 5; ++j) dpE[j] = (cc == 0) ? 0.0f : dp[j];

    rho = IDENT;
    const int lb = 82 * cc;
    const uint32_t ml = AM ? 0xFFFFu : (uint32_t)msk[cc];
    acc[0] = lstep<true>(xs, lb, (cc != 0) && ((ml & 1u) != 0), dp, tr, rho);
#pragma unroll
    for (int l = 1; l < 16; ++l) {
        uint32_t pk;
        if (AM) pk = lstep<false>(xs, lb + 5 * l, true, dp, tr, rho);
        else    pk = lstep<true >(xs, lb + 5 * l, ((ml >> l) & 1u) != 0, dp, tr, rho);
        if (l & 1) acc[l >> 1] |= pk << 16;
        else       acc[l >> 1]  = pk;
    }
}

__global__ __launch_bounds__(128, 3) void k_all(
    const float* __restrict__ x, const int* __restrict__ mask,
    const float* __restrict__ tf, float* __restrict__ out)
{
    __shared__ uint16_t xs[10496];   // 128 chunks * 82 halfwords (bf16, skewed)
    __shared__ uint16_t msk[NCHK];   // 16 mask bits per chunk
    __shared__ uint32_t tot[2];
    __shared__ float    part[2];
    __shared__ int      lastS;

    const int b = blockIdx.x, c = threadIdx.x;
    const int lane = c & 63, w = c >> 6;

    const float4* gx = (const float4*)(x + (size_t)b * (T_ * 5));
    const int4*   gm = (const int4*)(mask + (size_t)b * T_);

    // ---- deep-MLP staging: issue all loads before any writes ----
    float4 va[10]; int4 m4[4];
#pragma unroll
    for (int q = 0; q < 10; ++q) va[q] = gx[c + 128 * q];
#pragma unroll
    for (int q = 0; q < 4; ++q) m4[q] = gm[4 * c + q];
    __builtin_amdgcn_sched_barrier(0);
    float4 vb[10];
#pragma unroll
    for (int q = 0; q < 10; ++q) vb[q] = gx[c + 128 * (10 + q)];
    __builtin_amdgcn_sched_barrier(0);

    // writes: batch 1 (waits are incremental as values land)
#pragma unroll
    for (int q = 0; q < 10; ++q) {
        int fi = c + 128 * q;
        int e0 = 4 * fi;
        int k  = (e0 * 52429) >> 22;          // e0/80 (exact for e0 < 26000)
        int h0 = e0 + 2 * k;                  // +2 halfword pad per 16-step chunk
        *(uint32_t*)(xs + h0)     = cvtpk(va[q].x, va[q].y);
        *(uint32_t*)(xs + h0 + 2) = cvtpk(va[q].z, va[q].w);
    }
    uint32_t mb = 0;
#pragma unroll
    for (int q = 0; q < 4; ++q) {
        mb |= (m4[q].x ? 1u : 0u) << (4 * q);
        mb |= (m4[q].y ? 1u : 0u) << (4 * q + 1);
        mb |= (m4[q].z ? 1u : 0u) << (4 * q + 2);
        mb |= (m4[q].w ? 1u : 0u) << (4 * q + 3);
    }
    msk[c] = (uint16_t)mb;
    // writes: batch 2
#pragma unroll
    for (int q = 0; q < 10; ++q) {
        int fi = c + 128 * (10 + q);
        int e0 = 4 * fi;
        int k  = (e0 * 52429) >> 22;
        int h0 = e0 + 2 * k;
        *(uint32_t*)(xs + h0)     = cvtpk(vb[q].x, vb[q].y);
        *(uint32_t*)(xs + h0 + 2) = cvtpk(vb[q].z, vb[q].w);
    }

    float tr[5][5], ts[5], te[5];
#pragma unroll
    for (int i = 0; i < 5; ++i)
#pragma unroll
        for (int j = 0; j < 5; ++j) tr[i][j] = tf[i * TD + j];
#pragma unroll
    for (int j = 0; j < 5; ++j) ts[j] = tf[5 * TD + j];
#pragma unroll
    for (int j = 0; j < 5; ++j) te[j] = tf[j * TD + 6];

    const int allones = __syncthreads_and(mb == 0xFFFFu);

    float dp[5], dpE[5]; uint32_t acc[8], rho;
    if (allones) fwd<true >(xs, msk, c, tr, ts, dp, dpE, acc, rho);
    else         fwd<false>(xs, msk, c, tr, ts, dp, dpE, acc, rho);

    // exact per-chunk segment score of the decoded tree (within-lane telescoping)
    float svec[5];
#pragma unroll
    for (int j = 0; j < 5; ++j) {
        int r = (rho >> (3 * j)) & 7;
        float e = dpE[0];
        e = (r == 1) ? dpE[1] : e;
        e = (r == 2) ? dpE[2] : e;
        e = (r == 3) ? dpE[3] : e;
        e = (r == 4) ? dpE[4] : e;
        svec[j] = dp[j] - e;
    }

    // ---- intra-wave suffix composition (shfl, no barriers) ----
    uint32_t I = rho;
#pragma unroll
    for (int d = 1; d < 64; d <<= 1) {
        uint32_t oth = __shfl_down(I, d);
        uint32_t cm  = mcompose(I, oth);
        I = (lane + d < 64) ? cm : I;
    }
    if (lane == 0) tot[w] = I;
    if (c == NCHK - 1) {
        float best = dp[0] + te[0]; int last = 0;
#pragma unroll
        for (int j = 1; j < 5; ++j) {
            float s = dp[j] + te[j];
            if (s > best) { best = s; last = j; }
        }
        lastS = last;
    }
    __syncthreads();

    uint32_t Tw = (w == 0) ? tot[1] : IDENT;
    uint32_t Ex = __shfl_down(I, 1);
    uint32_t M  = (lane < 63) ? mcompose(Ex, Tw) : Tw;
    const int last = lastS;
    const int ec = (M >> (3 * last)) & 7;      // class at end of chunk c

    // ---- exact telescoped score: wave reduce + 2 partials ----
    {
        float v = svec[0];
        v = (ec == 1) ? svec[1] : v;
        v = (ec == 2) ? svec[2] : v;
        v = (ec == 3) ? svec[3] : v;
        v = (ec == 4) ? svec[4] : v;
        if (c == NCHK - 1) v += te[last];
#pragma unroll
        for (int off = 1; off < 64; off <<= 1) v += __shfl_xor(v, off);
        if (lane == 0) part[w] = v;
    }
    __syncthreads();
    if (c == 0) out[b] = part[0] + part[1];

    // ---- path decode from register bp ----
    float pv[16];
    int e = ec;
#pragma unroll
    for (int l = 15; l >= 0; --l) {
        pv[l] = (float)e;
        uint32_t p = (acc[l >> 1] >> (16 * (l & 1))) & 0xFFFFu;
        e = (p >> (3 * e)) & 7;
    }
    float* path = out + B_ + (size_t)b * T_ + c * 16;
#pragma unroll
    for (int q = 0; q < 4; ++q) {
        float4 v; v.x = pv[4*q]; v.y = pv[4*q+1]; v.z = pv[4*q+2]; v.w = pv[4*q+3];
        ((float4*)path)[q] = v;
    }
}

extern "C" void kernel_launch(void* const* d_in, const int* in_sizes, int n_in,
                              void* d_out, int out_size, void* d_ws, size_t ws_size,
                              hipStream_t stream) {
    const float* x         = (const float*)d_in[0];
    const int*   mask      = (const int*)d_in[1];
    const float* transform = (const float*)d_in[2];
    float*       out       = (float*)d_out;

    hipLaunchKernelGGL(k_all, dim3(B_), dim3(128), 0, stream,
                       x, mask, transform, out);
}